// Round 5
// baseline (453.742 us; speedup 1.0000x reference)
//
#include <hip/hip_runtime.h>
#include <hip/hip_bf16.h>

#define HD 256
#define NN 32768
#define NE 262144
#define NB 128
#define NM 512

typedef short bf16x8 __attribute__((ext_vector_type(8)));
typedef float f32x4 __attribute__((ext_vector_type(4)));
typedef unsigned short u16;
typedef unsigned short u16x8 __attribute__((ext_vector_type(8)));
typedef unsigned short u16x4 __attribute__((ext_vector_type(4)));

__device__ __forceinline__ float b2f(u16 u) {
    unsigned int i = ((unsigned int)u) << 16;
    float f; __builtin_memcpy(&f, &i, 4); return f;
}
__device__ __forceinline__ u16 f2b(float f) {
    unsigned int i; __builtin_memcpy(&i, &f, 4);
    return (u16)((i + 0x7FFFu + ((i >> 16) & 1u)) >> 16);
}

// ---------------- CSR build ----------------
__global__ __launch_bounds__(256) void k_hist(const int* __restrict__ dst, int* __restrict__ deg) {
    int e = blockIdx.x * 256 + threadIdx.x;
    if (e < NE) atomicAdd(&deg[dst[e]], 1);
}

__global__ __launch_bounds__(1024) void k_scan(const int* __restrict__ deg,
                                               int* __restrict__ offs, int* __restrict__ cur) {
    __shared__ int sums[1024];
    int t = threadIdx.x;
    int base = t * 32;
    int loc[32];
    int s = 0;
#pragma unroll
    for (int i = 0; i < 32; i++) { loc[i] = s; s += deg[base + i]; }
    sums[t] = s;
    __syncthreads();
    for (int o = 1; o < 1024; o <<= 1) {
        int v = 0;
        if (t >= o) v = sums[t - o];
        __syncthreads();
        if (t >= o) sums[t] += v;
        __syncthreads();
    }
    int pre = sums[t] - s;
#pragma unroll
    for (int i = 0; i < 32; i++) { int v = pre + loc[i]; offs[base + i] = v; cur[base + i] = v; }
    if (t == 1023) offs[NN] = sums[1023];
}

__global__ __launch_bounds__(256) void k_fill(const int* __restrict__ src, const int* __restrict__ dst,
                                              int* __restrict__ cur, int* __restrict__ csr) {
    int e = blockIdx.x * 256 + threadIdx.x;
    if (e < NE) {
        int p = atomicAdd(&cur[dst[e]], 1);
        csr[p] = src[e];
    }
}

__global__ __launch_bounds__(256) void k_sortcsr(const int* __restrict__ offs, int* __restrict__ csr) {
    int n = blockIdx.x * 256 + threadIdx.x;
    if (n >= NN) return;
    int o0 = offs[n], o1 = offs[n + 1];
    for (int i = o0 + 1; i < o1; i++) {
        int v = csr[i];
        int j = i - 1;
        while (j >= o0 && csr[j] > v) { csr[j + 1] = csr[j]; j--; }
        csr[j + 1] = v;
    }
}

// ---------------- tiled transpose + f32->bf16: Wt[n*K+k] = W[k*N+n], K=N=256 ----------------
__global__ __launch_bounds__(256) void k_transpose(const float* __restrict__ W, u16* __restrict__ Wt,
                                                   int K, int N) {
    __shared__ float tile[64][65];
    const int tiles_n = N >> 6;
    const int tk = blockIdx.x / tiles_n, tn = blockIdx.x % tiles_n;
    const int c = threadIdx.x & 63, r4 = threadIdx.x >> 6;
#pragma unroll
    for (int r = 0; r < 16; r++) {
        int k = tk * 64 + r * 4 + r4;
        tile[r * 4 + r4][c] = W[(size_t)k * N + tn * 64 + c];
    }
    __syncthreads();
#pragma unroll
    for (int r = 0; r < 16; r++) {
        int n = tn * 64 + r * 4 + r4;
        Wt[(size_t)n * K + tk * 64 + c] = f2b(tile[c][r * 4 + r4]);
    }
}

// ---------------- input projection ----------------
__global__ __launch_bounds__(256) void k_inproj(const float* __restrict__ x, const int* __restrict__ player,
                                                const float* __restrict__ Win, const float* __restrict__ bin,
                                                u16* __restrict__ h0) {
    const int j = threadIdx.x;
    const int node0 = blockIdx.x * 128;
    const int g = node0 >> 8;
    __shared__ float xs[128 * 32];
    for (int i = j; i < 128 * 32; i += 256) xs[i] = x[(size_t)node0 * 32 + i];
    float w[32];
#pragma unroll
    for (int k = 0; k < 32; k++) w[k] = Win[k * HD + j];
    const int pl = player[g];
    const float cadd = Win[(32 + pl) * HD + j] + bin[j];
    __syncthreads();
#pragma unroll 4
    for (int i = 0; i < 128; i++) {
        float a = cadd;
#pragma unroll
        for (int k = 0; k < 32; k++) a += xs[i * 32 + k] * w[k];
        h0[(size_t)(node0 + i) * HD + j] = f2b(a);
    }
}

// ---------------- fused GIN layer: reg agg + W streamed from L1/L2 + LN, no LDS, no barriers ----------------
// 256 threads / 4 waves; wave w handles rows bid*64 + w*16 + l15.
// mfma(Wfrag, hfrag): D col=l15 -> node row m; D row=lg*4+e -> channel fc*16+lg*4+e.
__global__ __launch_bounds__(256) void k_gin(const u16* __restrict__ h,
                                             const int* __restrict__ offs, const int* __restrict__ csr,
                                             const u16* __restrict__ Wt, const float* __restrict__ bias,
                                             const float* __restrict__ lng, const float* __restrict__ lnb,
                                             const u16* __restrict__ res, u16* __restrict__ hout) {
    const int lane = threadIdx.x & 63, wv = threadIdx.x >> 6;
    const int l15 = lane & 15, lg = lane >> 4;
    const int m = blockIdx.x * 64 + wv * 16 + l15;

    // --- aggregate self + neighbors into f32 regs (lane: cols ks*32+lg*8..+8) ---
    float vals[8][8];
    {
        const u16* hrow = h + (size_t)m * HD;
#pragma unroll
        for (int ks = 0; ks < 8; ks++) {
            u16x8 v = *(const u16x8*)(hrow + ks * 32 + lg * 8);
#pragma unroll
            for (int j = 0; j < 8; j++) vals[ks][j] = b2f(v[j]);
        }
    }
    const int o0 = offs[m], o1 = offs[m + 1];
    for (int e = o0; e < o1; e++) {
        const u16* srow = h + (size_t)csr[e] * HD;
#pragma unroll
        for (int ks = 0; ks < 8; ks++) {
            u16x8 v = *(const u16x8*)(srow + ks * 32 + lg * 8);
#pragma unroll
            for (int j = 0; j < 8; j++) vals[ks][j] += b2f(v[j]);
        }
    }
    bf16x8 afr[8];
#pragma unroll
    for (int ks = 0; ks < 8; ks++)
#pragma unroll
        for (int j = 0; j < 8; j++) afr[ks][j] = (short)f2b(vals[ks][j]);

    // --- GEMM: W-frags streamed from L1/L2 (same order in every wave -> broadcast reuse) ---
    f32x4 acc[16];
#pragma unroll
    for (int fc = 0; fc < 16; fc++) acc[fc] = (f32x4){0.f, 0.f, 0.f, 0.f};
#pragma unroll
    for (int ks = 0; ks < 8; ks++) {
#pragma unroll
        for (int fc = 0; fc < 16; fc++) {
            bf16x8 w = *(const bf16x8*)(Wt + (size_t)(fc * 16 + l15) * HD + ks * 32 + lg * 8);
            acc[fc] = __builtin_amdgcn_mfma_f32_16x16x32_bf16(w, afr[ks], acc[fc], 0, 0, 0);
        }
    }

    // --- bias + LN stats (row m lives in the 4 lanes sharing l15) ---
    float s = 0.f, q = 0.f;
#pragma unroll
    for (int fc = 0; fc < 16; fc++) {
        f32x4 b4 = *(const f32x4*)(bias + fc * 16 + lg * 4);
#pragma unroll
        for (int e = 0; e < 4; e++) {
            float z = acc[fc][e] + b4[e];
            acc[fc][e] = z;
            s += z; q += z * z;
        }
    }
    s += __shfl_xor(s, 16); s += __shfl_xor(s, 32);
    q += __shfl_xor(q, 16); q += __shfl_xor(q, 32);
    const float mean = s * (1.0f / HD);
    const float rinv = rsqrtf(q * (1.0f / HD) - mean * mean + 1e-5f);

    // --- LN (+res) + ReLU + store ---
    const bool hasRes = (res != nullptr);
#pragma unroll
    for (int fc = 0; fc < 16; fc++) {
        f32x4 g4 = *(const f32x4*)(lng + fc * 16 + lg * 4);
        f32x4 e4 = *(const f32x4*)(lnb + fc * 16 + lg * 4);
        float y[4];
#pragma unroll
        for (int e = 0; e < 4; e++) y[e] = (acc[fc][e] - mean) * rinv * g4[e] + e4[e];
        if (hasRes) {
            u16x4 r = *(const u16x4*)(res + (size_t)m * HD + fc * 16 + lg * 4);
#pragma unroll
            for (int e = 0; e < 4; e++) y[e] += b2f(r[e]);
        }
        u16x4 o;
#pragma unroll
        for (int e = 0; e < 4; e++) o[e] = f2b(fmaxf(y[e], 0.f));
        *(u16x4*)(hout + (size_t)m * HD + fc * 16 + lg * 4) = o;
    }
}

// ---------------- dense GEMM for policy precompute: hP = h @ Wt^T (+bias), no LDS ----------------
// grid 1024: blocks 0..511 -> Wta -> hP1 (+bp1); 512..1023 -> Wtb -> hP2.
__global__ __launch_bounds__(256) void k_dense(const u16* __restrict__ h,
                                               const u16* __restrict__ Wta, const u16* __restrict__ Wtb,
                                               const float* __restrict__ bp1,
                                               u16* __restrict__ hP1, u16* __restrict__ hP2) {
    const int lane = threadIdx.x & 63, wv = threadIdx.x >> 6;
    const int l15 = lane & 15, lg = lane >> 4;
    const int half = (blockIdx.x >= 512);
    const int m = (blockIdx.x & 511) * 64 + wv * 16 + l15;
    const u16* Wt = half ? Wtb : Wta;
    u16* outp = half ? hP2 : hP1;

    bf16x8 afr[8];
    {
        const u16* hrow = h + (size_t)m * HD;
#pragma unroll
        for (int ks = 0; ks < 8; ks++) afr[ks] = *(const bf16x8*)(hrow + ks * 32 + lg * 8);
    }

    f32x4 acc[16];
#pragma unroll
    for (int fc = 0; fc < 16; fc++) acc[fc] = (f32x4){0.f, 0.f, 0.f, 0.f};
#pragma unroll
    for (int ks = 0; ks < 8; ks++) {
#pragma unroll
        for (int fc = 0; fc < 16; fc++) {
            bf16x8 w = *(const bf16x8*)(Wt + (size_t)(fc * 16 + l15) * HD + ks * 32 + lg * 8);
            acc[fc] = __builtin_amdgcn_mfma_f32_16x16x32_bf16(w, afr[ks], acc[fc], 0, 0, 0);
        }
    }

#pragma unroll
    for (int fc = 0; fc < 16; fc++) {
        float b4[4] = {0.f, 0.f, 0.f, 0.f};
        if (!half) {
            f32x4 bb = *(const f32x4*)(bp1 + fc * 16 + lg * 4);
#pragma unroll
            for (int e = 0; e < 4; e++) b4[e] = bb[e];
        }
        u16x4 o;
#pragma unroll
        for (int e = 0; e < 4; e++) o[e] = f2b(acc[fc][e] + b4[e]);
        *(u16x4*)(outp + (size_t)m * HD + fc * 16 + lg * 4) = o;
    }
}

// ---------------- per-move: logit = relu(hP1[s] + hP2[t]) . Wp2 + bp2 ----------------
__global__ __launch_bounds__(256) void k_moves(const u16* __restrict__ hP1, const u16* __restrict__ hP2,
                                               const float* __restrict__ wp2, const float* __restrict__ bp2,
                                               const int* __restrict__ mov, float* __restrict__ out) {
    __shared__ float wp2L[256];
    wp2L[threadIdx.x] = wp2[threadIdx.x];
    __syncthreads();
    const int mi = blockIdx.x * 256 + threadIdx.x;
    int a = mov[(size_t)mi * 2], b = mov[(size_t)mi * 2 + 1];
    const bool vld = (a != -1) && (b != -1);
    const int s = a < 0 ? 0 : a, t = b < 0 ? 0 : b;
    const u16* r1 = hP1 + (size_t)s * HD;
    const u16* r2 = hP2 + (size_t)t * HD;
    float acc = 0.f;
#pragma unroll
    for (int c = 0; c < 32; c++) {
        u16x8 v1 = *(const u16x8*)(r1 + c * 8);
        u16x8 v2 = *(const u16x8*)(r2 + c * 8);
#pragma unroll
        for (int j = 0; j < 8; j++) {
            float z = b2f(v1[j]) + b2f(v2[j]);
            acc += fmaxf(z, 0.f) * wp2L[c * 8 + j];
        }
    }
    out[mi] = vld ? acc + bp2[0] : -1e9f;
}

// ---------------- global mean pool (partials: 4 chunks of 64 rows per graph) ----------------
__global__ __launch_bounds__(256) void k_pool4(const u16* __restrict__ h, float* __restrict__ gep) {
    const int g = blockIdx.x >> 2, c = blockIdx.x & 3, j = threadIdx.x;
    const u16* p = h + ((size_t)g * 256 + c * 64) * HD + j;
    float s = 0.f;
#pragma unroll 8
    for (int i = 0; i < 64; i++) s += b2f(p[(size_t)i * HD]);
    gep[(size_t)blockIdx.x * HD + j] = s;
}

// ---------------- value head (reduces pool partials; deterministic) ----------------
__global__ __launch_bounds__(256) void k_value(const float* __restrict__ gep,
                                               const float* __restrict__ W1, const float* __restrict__ b1,
                                               const float* __restrict__ W2, const float* __restrict__ b2p,
                                               const float* __restrict__ g1, const float* __restrict__ be1,
                                               const float* __restrict__ m1, const float* __restrict__ v1,
                                               const float* __restrict__ g2, const float* __restrict__ be2,
                                               const float* __restrict__ m2, const float* __restrict__ v2,
                                               const float* __restrict__ Wv, const float* __restrict__ bv,
                                               float* __restrict__ out) {
    int g = blockIdx.x, j = threadIdx.x;
    __shared__ float buf[256];
    __shared__ float red[4];
    buf[j] = (gep[(size_t)(g * 4 + 0) * HD + j] + gep[(size_t)(g * 4 + 1) * HD + j] +
              gep[(size_t)(g * 4 + 2) * HD + j] + gep[(size_t)(g * 4 + 3) * HD + j]) * (1.0f / 256.0f);
    __syncthreads();
    float z = 0.f;
    for (int k = 0; k < HD; k++) z += buf[k] * W1[k * HD + j];
    z += b1[j];
    z = (z - m1[j]) * rsqrtf(v1[j] + 1e-5f) * g1[j] + be1[j];
    z = fmaxf(z, 0.f);
    __syncthreads();
    buf[j] = z;
    __syncthreads();
    float z2 = 0.f;
    for (int k = 0; k < HD; k++) z2 += buf[k] * W2[k * HD + j];
    z2 += b2p[j];
    z2 = (z2 - m2[j]) * rsqrtf(v2[j] + 1e-5f) * g2[j] + be2[j];
    z2 = fmaxf(z2, 0.f);
    float pv = z2 * Wv[j];
#pragma unroll
    for (int m = 1; m < 64; m <<= 1) pv += __shfl_xor(pv, m, 64);
    if ((j & 63) == 0) red[j >> 6] = pv;
    __syncthreads();
    if (j == 0) out[g] = tanhf(red[0] + red[1] + red[2] + red[3] + bv[0]);
}

extern "C" void kernel_launch(void* const* d_in, const int* in_sizes, int n_in,
                              void* d_out, int out_size, void* d_ws, size_t ws_size,
                              hipStream_t stream) {
    const float* x    = (const float*)d_in[0];
    const int* eidx   = (const int*)d_in[1];
    const int* mov    = (const int*)d_in[2];
    const int* player = (const int*)d_in[3];
    const float* Win  = (const float*)d_in[5];
    const float* b_in = (const float*)d_in[6];
    const float* Wg1 = (const float*)d_in[7],  *bg1 = (const float*)d_in[8];
    const float* Wg2 = (const float*)d_in[9],  *bg2 = (const float*)d_in[10];
    const float* Wg3 = (const float*)d_in[11], *bg3 = (const float*)d_in[12];
    const float* ln1g = (const float*)d_in[13], *ln1b = (const float*)d_in[14];
    const float* ln2g = (const float*)d_in[15], *ln2b = (const float*)d_in[16];
    const float* ln3g = (const float*)d_in[17], *ln3b = (const float*)d_in[18];
    const float* Wfc1 = (const float*)d_in[19], *bfc1 = (const float*)d_in[20];
    const float* Wfc2 = (const float*)d_in[21], *bfc2 = (const float*)d_in[22];
    const float* bn1g = (const float*)d_in[23], *bn1b = (const float*)d_in[24];
    const float* bn1m = (const float*)d_in[25], *bn1v = (const float*)d_in[26];
    const float* bn2g = (const float*)d_in[27], *bn2b = (const float*)d_in[28];
    const float* bn2m = (const float*)d_in[29], *bn2v = (const float*)d_in[30];
    const float* Wp1 = (const float*)d_in[31], *bp1 = (const float*)d_in[32];
    const float* Wp2 = (const float*)d_in[33], *bp2 = (const float*)d_in[34];
    const float* Wv  = (const float*)d_in[35], *bv  = (const float*)d_in[36];

    char* ws = (char*)d_ws;
    size_t off = 0;
    auto alloc = [&](size_t bytes) {
        size_t p = off;
        off = (off + bytes + 255) & ~(size_t)255;
        return (void*)(ws + p);
    };
    u16* h0   = (u16*)alloc((size_t)NN * HD * 2);
    u16* hA   = (u16*)alloc((size_t)NN * HD * 2);
    u16* hB   = (u16*)alloc((size_t)NN * HD * 2);
    u16* Wt1  = (u16*)alloc((size_t)HD * HD * 2);
    u16* Wt2  = (u16*)alloc((size_t)HD * HD * 2);
    u16* Wt3  = (u16*)alloc((size_t)HD * HD * 2);
    u16* Wta  = (u16*)alloc((size_t)HD * HD * 2);
    u16* Wtb  = (u16*)alloc((size_t)HD * HD * 2);
    int* deg  = (int*)alloc((size_t)NN * 4);
    int* offs = (int*)alloc((size_t)(NN + 1) * 4);
    int* cur  = (int*)alloc((size_t)NN * 4);
    int* csr  = (int*)alloc((size_t)NE * 4);
    float* gep = (float*)alloc((size_t)NB * 4 * HD * 4);

    const int* esrc = eidx;
    const int* edst = eidx + NE;

    hipMemsetAsync(deg, 0, (size_t)NN * 4, stream);
    k_hist<<<NE / 256, 256, 0, stream>>>(edst, deg);
    k_scan<<<1, 1024, 0, stream>>>(deg, offs, cur);
    k_fill<<<NE / 256, 256, 0, stream>>>(esrc, edst, cur, csr);
    k_sortcsr<<<NN / 256, 256, 0, stream>>>(offs, csr);

    k_transpose<<<16, 256, 0, stream>>>(Wg1, Wt1, HD, HD);
    k_transpose<<<16, 256, 0, stream>>>(Wg2, Wt2, HD, HD);
    k_transpose<<<16, 256, 0, stream>>>(Wg3, Wt3, HD, HD);
    k_transpose<<<16, 256, 0, stream>>>(Wp1, Wta, HD, HD);
    k_transpose<<<16, 256, 0, stream>>>(Wp1 + HD * HD, Wtb, HD, HD);

    k_inproj<<<NN / 128, 256, 0, stream>>>(x, player, Win, b_in, h0);

    k_gin<<<NN / 64, 256, 0, stream>>>(h0, offs, csr, Wt1, bg1, ln1g, ln1b, nullptr, hA);
    k_gin<<<NN / 64, 256, 0, stream>>>(hA, offs, csr, Wt2, bg2, ln2g, ln2b, nullptr, hB);
    k_gin<<<NN / 64, 256, 0, stream>>>(hB, offs, csr, Wt3, bg3, ln3g, ln3b, h0, hA);

    // reuse hB as hP1, h0 as hP2 (both dead after layer 3)
    u16* hP1 = hB;
    u16* hP2 = h0;

    k_pool4<<<NB * 4, 256, 0, stream>>>(hA, gep);
    k_value<<<NB, 256, 0, stream>>>(gep, Wfc1, bfc1, Wfc2, bfc2,
                                    bn1g, bn1b, bn1m, bn1v, bn2g, bn2b, bn2m, bn2v,
                                    Wv, bv, ((float*)d_out) + NB * NM);

    k_dense<<<1024, 256, 0, stream>>>(hA, Wta, Wtb, bp1, hP1, hP2);
    k_moves<<<(NB * NM) / 256, 256, 0, stream>>>(hP1, hP2, Wp2, bp2, mov, (float*)d_out);
}

// Round 6
// 309.970 us; speedup vs baseline: 1.4638x; 1.4638x over previous
//
#include <hip/hip_runtime.h>
#include <hip/hip_bf16.h>

#define HD 256
#define NN 32768
#define NE 262144
#define NB 128
#define NM 512

typedef short bf16x8 __attribute__((ext_vector_type(8)));
typedef float f32x4 __attribute__((ext_vector_type(4)));
typedef unsigned short u16;
typedef unsigned short u16x8 __attribute__((ext_vector_type(8)));
typedef unsigned short u16x4 __attribute__((ext_vector_type(4)));

__device__ __forceinline__ float b2f(u16 u) {
    unsigned int i = ((unsigned int)u) << 16;
    float f; __builtin_memcpy(&f, &i, 4); return f;
}
__device__ __forceinline__ u16 f2b(float f) {
    unsigned int i; __builtin_memcpy(&i, &f, 4);
    return (u16)((i + 0x7FFFu + ((i >> 16) & 1u)) >> 16);
}

// ---------------- CSR build ----------------
__global__ __launch_bounds__(256) void k_hist(const int* __restrict__ dst, int* __restrict__ deg) {
    int e = blockIdx.x * 256 + threadIdx.x;
    if (e < NE) atomicAdd(&deg[dst[e]], 1);
}

__global__ __launch_bounds__(1024) void k_scan(const int* __restrict__ deg,
                                               int* __restrict__ offs, int* __restrict__ cur) {
    __shared__ int sums[1024];
    int t = threadIdx.x;
    int base = t * 32;
    int loc[32];
    int s = 0;
#pragma unroll
    for (int i = 0; i < 32; i++) { loc[i] = s; s += deg[base + i]; }
    sums[t] = s;
    __syncthreads();
    for (int o = 1; o < 1024; o <<= 1) {
        int v = 0;
        if (t >= o) v = sums[t - o];
        __syncthreads();
        if (t >= o) sums[t] += v;
        __syncthreads();
    }
    int pre = sums[t] - s;
#pragma unroll
    for (int i = 0; i < 32; i++) { int v = pre + loc[i]; offs[base + i] = v; cur[base + i] = v; }
    if (t == 1023) offs[NN] = sums[1023];
}

__global__ __launch_bounds__(256) void k_fill(const int* __restrict__ src, const int* __restrict__ dst,
                                              int* __restrict__ cur, int* __restrict__ csr) {
    int e = blockIdx.x * 256 + threadIdx.x;
    if (e < NE) {
        int p = atomicAdd(&cur[dst[e]], 1);
        csr[p] = src[e];
    }
}

__global__ __launch_bounds__(256) void k_sortcsr(const int* __restrict__ offs, int* __restrict__ csr) {
    int n = blockIdx.x * 256 + threadIdx.x;
    if (n >= NN) return;
    int o0 = offs[n], o1 = offs[n + 1];
    for (int i = o0 + 1; i < o1; i++) {
        int v = csr[i];
        int j = i - 1;
        while (j >= o0 && csr[j] > v) { csr[j + 1] = csr[j]; j--; }
        csr[j + 1] = v;
    }
}

// ---------------- tiled transpose + f32->bf16 + LDS-image pre-swizzle ----------------
// Produces Wsw: row n (256 u16), element k stored at chunk ((k>>3) ^ ((n&7)<<2)), pos (k&7).
// So a linear copy of Wsw into LDS yields the bank-conflict-free read layout.
__global__ __launch_bounds__(256) void k_transpose_sw(const float* __restrict__ W, u16* __restrict__ Wsw,
                                                      int K, int N) {
    __shared__ float tile[64][65];
    const int tiles_n = N >> 6;
    const int tk = blockIdx.x / tiles_n, tn = blockIdx.x % tiles_n;
    const int c = threadIdx.x & 63, r4 = threadIdx.x >> 6;
#pragma unroll
    for (int r = 0; r < 16; r++) {
        int k = tk * 64 + r * 4 + r4;
        tile[r * 4 + r4][c] = W[(size_t)k * N + tn * 64 + c];
    }
    __syncthreads();
#pragma unroll
    for (int r = 0; r < 16; r++) {
        int n = tn * 64 + r * 4 + r4;           // output row
        int k = tk * 64 + c;                     // output col
        int chunk = (k >> 3) ^ ((n & 7) << 2);   // 32-slot XOR swizzle
        Wsw[(size_t)n * 256 + chunk * 8 + (k & 7)] = f2b(tile[c][r * 4 + r4]);
    }
}

// ---------------- input projection ----------------
__global__ __launch_bounds__(256) void k_inproj(const float* __restrict__ x, const int* __restrict__ player,
                                                const float* __restrict__ Win, const float* __restrict__ bin,
                                                u16* __restrict__ h0) {
    const int j = threadIdx.x;
    const int node0 = blockIdx.x * 128;
    const int g = node0 >> 8;
    __shared__ float xs[128 * 32];
    for (int i = j; i < 128 * 32; i += 256) xs[i] = x[(size_t)node0 * 32 + i];
    float w[32];
#pragma unroll
    for (int k = 0; k < 32; k++) w[k] = Win[k * HD + j];
    const int pl = player[g];
    const float cadd = Win[(32 + pl) * HD + j] + bin[j];
    __syncthreads();
#pragma unroll 4
    for (int i = 0; i < 128; i++) {
        float a = cadd;
#pragma unroll
        for (int k = 0; k < 32; k++) a += xs[i * 32 + k] * w[k];
        h0[(size_t)(node0 + i) * HD + j] = f2b(a);
    }
}

// ---------------- aggregation: hin[n] = h[n] + sum_{e:dst=n} h[csr[e]] ----------------
// 32 lanes per node, 16B/lane; 8 nodes/block, 4096 blocks -> max TLP for the random gather.
__global__ __launch_bounds__(256) void k_agg(const u16* __restrict__ h, const int* __restrict__ offs,
                                             const int* __restrict__ csr, u16* __restrict__ hin) {
    const int n = blockIdx.x * 8 + (threadIdx.x >> 5);
    const int fo = (threadIdx.x & 31) * 8;
    const u16* hp = h + fo;
    u16x8 sv = *(const u16x8*)(hp + (size_t)n * HD);
    float a[8];
#pragma unroll
    for (int j = 0; j < 8; j++) a[j] = b2f(sv[j]);
    const int o0 = offs[n], o1 = offs[n + 1];
    int e = o0;
    for (; e + 2 <= o1; e += 2) {
        int s0 = csr[e], s1 = csr[e + 1];
        u16x8 v0 = *(const u16x8*)(hp + (size_t)s0 * HD);
        u16x8 v1 = *(const u16x8*)(hp + (size_t)s1 * HD);
#pragma unroll
        for (int j = 0; j < 8; j++) a[j] += b2f(v0[j]);
#pragma unroll
        for (int j = 0; j < 8; j++) a[j] += b2f(v1[j]);
    }
    if (e < o1) {
        u16x8 v0 = *(const u16x8*)(hp + (size_t)csr[e] * HD);
#pragma unroll
        for (int j = 0; j < 8; j++) a[j] += b2f(v0[j]);
    }
    u16x8 o;
#pragma unroll
    for (int j = 0; j < 8; j++) o[j] = f2b(a[j]);
    *(u16x8*)(hin + (size_t)n * HD + fo) = o;
}

// ---------------- GEMM + bias + LayerNorm (+res) + ReLU; W staged once via global_load_lds ----------------
// 512 threads / 8 waves; 128 rows/block; grid 256. Single barrier.
// mfma(Wfrag, hfrag): D col=l15 -> node row m; D row=lg*4+e -> channel fc*16+lg*4+e.
__global__ __launch_bounds__(512) void k_mmln(const u16* __restrict__ hin, const u16* __restrict__ Wsw,
                                              const float* __restrict__ bias, const float* __restrict__ lng,
                                              const float* __restrict__ lnb, const u16* __restrict__ res,
                                              u16* __restrict__ hout) {
    const int tid = threadIdx.x;
    const int lane = tid & 63, wv = tid >> 6;
    const int l15 = lane & 15, lg = lane >> 4;
    const int m = blockIdx.x * 128 + wv * 16 + l15;

    __shared__ char Wl[256 * 512];   // 128 KiB pre-swizzled W image

    // stage W: linear async copy (image already swizzled)
#pragma unroll
    for (int i = 0; i < 16; i++)
        __builtin_amdgcn_global_load_lds((const unsigned int*)(Wsw + tid * 8 + i * 4096),
                                         (unsigned int*)(Wl + tid * 16 + i * 8192), 16, 0, 0);

    // A-fragments from global (overlaps staging)
    bf16x8 afr[8];
    {
        const u16* hrow = hin + (size_t)m * HD;
#pragma unroll
        for (int ks = 0; ks < 8; ks++) afr[ks] = *(const bf16x8*)(hrow + ks * 32 + lg * 8);
    }

    __syncthreads();

    // MFMA: conflict-free swizzled ds_read_b128
    f32x4 acc[16];
#pragma unroll
    for (int fc = 0; fc < 16; fc++) acc[fc] = (f32x4){0.f, 0.f, 0.f, 0.f};
    const int rsw = (l15 & 7) << 6;
#pragma unroll
    for (int ks = 0; ks < 8; ks++) {
#pragma unroll
        for (int fc = 0; fc < 16; fc++) {
            const char* wp = Wl + (fc * 16 + l15) * 512 + ((((ks * 4 + lg) << 4)) ^ rsw);
            bf16x8 w = *(const bf16x8*)wp;
            acc[fc] = __builtin_amdgcn_mfma_f32_16x16x32_bf16(w, afr[ks], acc[fc], 0, 0, 0);
        }
    }

    // bias + LN stats (row m lives in 4 lanes sharing l15)
    float s = 0.f, q = 0.f;
#pragma unroll
    for (int fc = 0; fc < 16; fc++) {
        f32x4 b4 = *(const f32x4*)(bias + fc * 16 + lg * 4);
#pragma unroll
        for (int e = 0; e < 4; e++) {
            float z = acc[fc][e] + b4[e];
            acc[fc][e] = z;
            s += z; q += z * z;
        }
    }
    s += __shfl_xor(s, 16); s += __shfl_xor(s, 32);
    q += __shfl_xor(q, 16); q += __shfl_xor(q, 32);
    const float mean = s * (1.0f / HD);
    const float rinv = rsqrtf(q * (1.0f / HD) - mean * mean + 1e-5f);

    const bool hasRes = (res != nullptr);
#pragma unroll
    for (int fc = 0; fc < 16; fc++) {
        f32x4 g4 = *(const f32x4*)(lng + fc * 16 + lg * 4);
        f32x4 e4 = *(const f32x4*)(lnb + fc * 16 + lg * 4);
        float y[4];
#pragma unroll
        for (int e = 0; e < 4; e++) y[e] = (acc[fc][e] - mean) * rinv * g4[e] + e4[e];
        if (hasRes) {
            u16x4 r = *(const u16x4*)(res + (size_t)m * HD + fc * 16 + lg * 4);
#pragma unroll
            for (int e = 0; e < 4; e++) y[e] += b2f(r[e]);
        }
        u16x4 o;
#pragma unroll
        for (int e = 0; e < 4; e++) o[e] = f2b(fmaxf(y[e], 0.f));
        *(u16x4*)(hout + (size_t)m * HD + fc * 16 + lg * 4) = o;
    }
}

// ---------------- dense GEMM for policy precompute (same structure, no LN) ----------------
// grid 512: blocks 0..255 -> Wsa -> hP1 (+bp1); 256..511 -> Wsb -> hP2.
__global__ __launch_bounds__(512) void k_dense(const u16* __restrict__ h,
                                               const u16* __restrict__ Wsa, const u16* __restrict__ Wsb,
                                               const float* __restrict__ bp1,
                                               u16* __restrict__ hP1, u16* __restrict__ hP2) {
    const int tid = threadIdx.x;
    const int lane = tid & 63, wv = tid >> 6;
    const int l15 = lane & 15, lg = lane >> 4;
    const int half = (blockIdx.x >= 256);
    const int m = (blockIdx.x & 255) * 128 + wv * 16 + l15;
    const u16* Wsw = half ? Wsb : Wsa;
    u16* outp = half ? hP2 : hP1;

    __shared__ char Wl[256 * 512];

#pragma unroll
    for (int i = 0; i < 16; i++)
        __builtin_amdgcn_global_load_lds((const unsigned int*)(Wsw + tid * 8 + i * 4096),
                                         (unsigned int*)(Wl + tid * 16 + i * 8192), 16, 0, 0);

    bf16x8 afr[8];
    {
        const u16* hrow = h + (size_t)m * HD;
#pragma unroll
        for (int ks = 0; ks < 8; ks++) afr[ks] = *(const bf16x8*)(hrow + ks * 32 + lg * 8);
    }

    __syncthreads();

    f32x4 acc[16];
#pragma unroll
    for (int fc = 0; fc < 16; fc++) acc[fc] = (f32x4){0.f, 0.f, 0.f, 0.f};
    const int rsw = (l15 & 7) << 6;
#pragma unroll
    for (int ks = 0; ks < 8; ks++) {
#pragma unroll
        for (int fc = 0; fc < 16; fc++) {
            const char* wp = Wl + (fc * 16 + l15) * 512 + ((((ks * 4 + lg) << 4)) ^ rsw);
            bf16x8 w = *(const bf16x8*)wp;
            acc[fc] = __builtin_amdgcn_mfma_f32_16x16x32_bf16(w, afr[ks], acc[fc], 0, 0, 0);
        }
    }

#pragma unroll
    for (int fc = 0; fc < 16; fc++) {
        float b4[4] = {0.f, 0.f, 0.f, 0.f};
        if (!half) {
            f32x4 bb = *(const f32x4*)(bp1 + fc * 16 + lg * 4);
#pragma unroll
            for (int e = 0; e < 4; e++) b4[e] = bb[e];
        }
        u16x4 o;
#pragma unroll
        for (int e = 0; e < 4; e++) o[e] = f2b(acc[fc][e] + b4[e]);
        *(u16x4*)(outp + (size_t)m * HD + fc * 16 + lg * 4) = o;
    }
}

// ---------------- per-move: logit = relu(hP1[s] + hP2[t]) . Wp2 + bp2 ----------------
__global__ __launch_bounds__(256) void k_moves(const u16* __restrict__ hP1, const u16* __restrict__ hP2,
                                               const float* __restrict__ wp2, const float* __restrict__ bp2,
                                               const int* __restrict__ mov, float* __restrict__ out) {
    __shared__ float wp2L[256];
    wp2L[threadIdx.x] = wp2[threadIdx.x];
    __syncthreads();
    const int mi = blockIdx.x * 256 + threadIdx.x;
    int a = mov[(size_t)mi * 2], b = mov[(size_t)mi * 2 + 1];
    const bool vld = (a != -1) && (b != -1);
    const int s = a < 0 ? 0 : a, t = b < 0 ? 0 : b;
    const u16* r1 = hP1 + (size_t)s * HD;
    const u16* r2 = hP2 + (size_t)t * HD;
    float acc = 0.f;
#pragma unroll
    for (int c = 0; c < 32; c++) {
        u16x8 v1 = *(const u16x8*)(r1 + c * 8);
        u16x8 v2 = *(const u16x8*)(r2 + c * 8);
#pragma unroll
        for (int j = 0; j < 8; j++) {
            float z = b2f(v1[j]) + b2f(v2[j]);
            acc += fmaxf(z, 0.f) * wp2L[c * 8 + j];
        }
    }
    out[mi] = vld ? acc + bp2[0] : -1e9f;
}

// ---------------- global mean pool partials ----------------
__global__ __launch_bounds__(256) void k_pool4(const u16* __restrict__ h, float* __restrict__ gep) {
    const int g = blockIdx.x >> 2, c = blockIdx.x & 3, j = threadIdx.x;
    const u16* p = h + ((size_t)g * 256 + c * 64) * HD + j;
    float s = 0.f;
#pragma unroll 8
    for (int i = 0; i < 64; i++) s += b2f(p[(size_t)i * HD]);
    gep[(size_t)blockIdx.x * HD + j] = s;
}

// ---------------- value head ----------------
__global__ __launch_bounds__(256) void k_value(const float* __restrict__ gep,
                                               const float* __restrict__ W1, const float* __restrict__ b1,
                                               const float* __restrict__ W2, const float* __restrict__ b2p,
                                               const float* __restrict__ g1, const float* __restrict__ be1,
                                               const float* __restrict__ m1, const float* __restrict__ v1,
                                               const float* __restrict__ g2, const float* __restrict__ be2,
                                               const float* __restrict__ m2, const float* __restrict__ v2,
                                               const float* __restrict__ Wv, const float* __restrict__ bv,
                                               float* __restrict__ out) {
    int g = blockIdx.x, j = threadIdx.x;
    __shared__ float buf[256];
    __shared__ float red[4];
    buf[j] = (gep[(size_t)(g * 4 + 0) * HD + j] + gep[(size_t)(g * 4 + 1) * HD + j] +
              gep[(size_t)(g * 4 + 2) * HD + j] + gep[(size_t)(g * 4 + 3) * HD + j]) * (1.0f / 256.0f);
    __syncthreads();
    float z = 0.f;
    for (int k = 0; k < HD; k++) z += buf[k] * W1[k * HD + j];
    z += b1[j];
    z = (z - m1[j]) * rsqrtf(v1[j] + 1e-5f) * g1[j] + be1[j];
    z = fmaxf(z, 0.f);
    __syncthreads();
    buf[j] = z;
    __syncthreads();
    float z2 = 0.f;
    for (int k = 0; k < HD; k++) z2 += buf[k] * W2[k * HD + j];
    z2 += b2p[j];
    z2 = (z2 - m2[j]) * rsqrtf(v2[j] + 1e-5f) * g2[j] + be2[j];
    z2 = fmaxf(z2, 0.f);
    float pv = z2 * Wv[j];
#pragma unroll
    for (int m = 1; m < 64; m <<= 1) pv += __shfl_xor(pv, m, 64);
    if ((j & 63) == 0) red[j >> 6] = pv;
    __syncthreads();
    if (j == 0) out[g] = tanhf(red[0] + red[1] + red[2] + red[3] + bv[0]);
}

extern "C" void kernel_launch(void* const* d_in, const int* in_sizes, int n_in,
                              void* d_out, int out_size, void* d_ws, size_t ws_size,
                              hipStream_t stream) {
    const float* x    = (const float*)d_in[0];
    const int* eidx   = (const int*)d_in[1];
    const int* mov    = (const int*)d_in[2];
    const int* player = (const int*)d_in[3];
    const float* Win  = (const float*)d_in[5];
    const float* b_in = (const float*)d_in[6];
    const float* Wg1 = (const float*)d_in[7],  *bg1 = (const float*)d_in[8];
    const float* Wg2 = (const float*)d_in[9],  *bg2 = (const float*)d_in[10];
    const float* Wg3 = (const float*)d_in[11], *bg3 = (const float*)d_in[12];
    const float* ln1g = (const float*)d_in[13], *ln1b = (const float*)d_in[14];
    const float* ln2g = (const float*)d_in[15], *ln2b = (const float*)d_in[16];
    const float* ln3g = (const float*)d_in[17], *ln3b = (const float*)d_in[18];
    const float* Wfc1 = (const float*)d_in[19], *bfc1 = (const float*)d_in[20];
    const float* Wfc2 = (const float*)d_in[21], *bfc2 = (const float*)d_in[22];
    const float* bn1g = (const float*)d_in[23], *bn1b = (const float*)d_in[24];
    const float* bn1m = (const float*)d_in[25], *bn1v = (const float*)d_in[26];
    const float* bn2g = (const float*)d_in[27], *bn2b = (const float*)d_in[28];
    const float* bn2m = (const float*)d_in[29], *bn2v = (const float*)d_in[30];
    const float* Wp1 = (const float*)d_in[31], *bp1 = (const float*)d_in[32];
    const float* Wp2 = (const float*)d_in[33], *bp2 = (const float*)d_in[34];
    const float* Wv  = (const float*)d_in[35], *bv  = (const float*)d_in[36];

    char* ws = (char*)d_ws;
    size_t off = 0;
    auto alloc = [&](size_t bytes) {
        size_t p = off;
        off = (off + bytes + 255) & ~(size_t)255;
        return (void*)(ws + p);
    };
    u16* h0   = (u16*)alloc((size_t)NN * HD * 2);
    u16* hA   = (u16*)alloc((size_t)NN * HD * 2);
    u16* hB   = (u16*)alloc((size_t)NN * HD * 2);
    u16* hin  = (u16*)alloc((size_t)NN * HD * 2);
    u16* Ws1  = (u16*)alloc((size_t)HD * HD * 2);
    u16* Ws2  = (u16*)alloc((size_t)HD * HD * 2);
    u16* Ws3  = (u16*)alloc((size_t)HD * HD * 2);
    u16* Wsa  = (u16*)alloc((size_t)HD * HD * 2);
    u16* Wsb  = (u16*)alloc((size_t)HD * HD * 2);
    int* deg  = (int*)alloc((size_t)NN * 4);
    int* offs = (int*)alloc((size_t)(NN + 1) * 4);
    int* cur  = (int*)alloc((size_t)NN * 4);
    int* csr  = (int*)alloc((size_t)NE * 4);
    float* gep = (float*)alloc((size_t)NB * 4 * HD * 4);

    const int* esrc = eidx;
    const int* edst = eidx + NE;

    hipMemsetAsync(deg, 0, (size_t)NN * 4, stream);
    k_hist<<<NE / 256, 256, 0, stream>>>(edst, deg);
    k_scan<<<1, 1024, 0, stream>>>(deg, offs, cur);
    k_fill<<<NE / 256, 256, 0, stream>>>(esrc, edst, cur, csr);
    k_sortcsr<<<NN / 256, 256, 0, stream>>>(offs, csr);

    k_transpose_sw<<<16, 256, 0, stream>>>(Wg1, Ws1, HD, HD);
    k_transpose_sw<<<16, 256, 0, stream>>>(Wg2, Ws2, HD, HD);
    k_transpose_sw<<<16, 256, 0, stream>>>(Wg3, Ws3, HD, HD);
    k_transpose_sw<<<16, 256, 0, stream>>>(Wp1, Wsa, HD, HD);
    k_transpose_sw<<<16, 256, 0, stream>>>(Wp1 + HD * HD, Wsb, HD, HD);

    k_inproj<<<NN / 128, 256, 0, stream>>>(x, player, Win, b_in, h0);

    // layer 1
    k_agg<<<NN / 8, 256, 0, stream>>>(h0, offs, csr, hin);
    k_mmln<<<NN / 128, 512, 0, stream>>>(hin, Ws1, bg1, ln1g, ln1b, nullptr, hA);
    // layer 2
    k_agg<<<NN / 8, 256, 0, stream>>>(hA, offs, csr, hin);
    k_mmln<<<NN / 128, 512, 0, stream>>>(hin, Ws2, bg2, ln2g, ln2b, nullptr, hB);
    // layer 3 (+residual)
    k_agg<<<NN / 8, 256, 0, stream>>>(hB, offs, csr, hin);
    k_mmln<<<NN / 128, 512, 0, stream>>>(hin, Ws3, bg3, ln3g, ln3b, h0, hA);

    // hin, h0, hB dead -> reuse for policy precompute
    u16* hP1 = h0;
    u16* hP2 = hB;

    k_pool4<<<NB * 4, 256, 0, stream>>>(hA, gep);
    k_value<<<NB, 256, 0, stream>>>(gep, Wfc1, bfc1, Wfc2, bfc2,
                                    bn1g, bn1b, bn1m, bn1v, bn2g, bn2b, bn2m, bn2v,
                                    Wv, bv, ((float*)d_out) + NB * NM);

    k_dense<<<512, 512, 0, stream>>>(hA, Wsa, Wsb, bp1, hP1, hP2);
    k_moves<<<(NB * NM) / 256, 256, 0, stream>>>(hP1, hP2, Wp2, bp2, mov, (float*)d_out);
}